// Round 4
// baseline (211.738 us; speedup 1.0000x reference)
//
#include <hip/hip_runtime.h>
#include <stdint.h>

#define FDIM 256
#define KDIM 1024   // 4*F : [x | h | Tx1 | Tx2]

typedef __attribute__((ext_vector_type(8))) short short8;
typedef __attribute__((ext_vector_type(4))) float floatx4;

#define GLOBAL_AS __attribute__((address_space(1)))
#define LDS_AS    __attribute__((address_space(3)))

static __device__ __forceinline__ unsigned short f2bf(float f) {
    unsigned int u = __float_as_uint(f);
    unsigned int r = (u + 0x7FFFu + ((u >> 16) & 1u)) >> 16;
    return (unsigned short)r;
}
static __device__ __forceinline__ float bf2f(unsigned short s) {
    return __uint_as_float(((unsigned int)s) << 16);
}
static __device__ __forceinline__ float sig(float x) {
    return 1.f / (1.f + __expf(-x));
}

// ---------------- setup kernels ----------------

__global__ void k_degcnt(const int* __restrict__ src, const int* __restrict__ dst,
                         const float* __restrict__ ew, float* deg, int* cnt, int e) {
    int i = blockIdx.x * blockDim.x + threadIdx.x;
    if (i < e) {
        atomicAdd(&deg[src[i]], ew[i]);
        atomicAdd(&cnt[dst[i]], 1);
    }
}

// hierarchical scan, stage 1: per-1024-block inclusive scan -> offs[i+1], block total -> part[b]
__launch_bounds__(1024)
__global__ void k_scan1(const int* __restrict__ cnt, int* __restrict__ offs,
                        int* __restrict__ part, int n) {
    __shared__ int wsum[16];
    int b = blockIdx.x;
    int i = b * 1024 + (int)threadIdx.x;
    int lane = threadIdx.x & 63;
    int wid = threadIdx.x >> 6;
    int x = (i < n) ? cnt[i] : 0;
#pragma unroll
    for (int s = 1; s < 64; s <<= 1) {
        int t = __shfl_up(x, s);
        if (lane >= s) x += t;
    }
    if (lane == 63) wsum[wid] = x;
    __syncthreads();
    if (wid == 0) {
        int y = (lane < 16) ? wsum[lane] : 0;
#pragma unroll
        for (int s = 1; s < 16; s <<= 1) {
            int t = __shfl_up(y, s);
            if (lane >= s) y += t;
        }
        if (lane < 16) wsum[lane] = y;
    }
    __syncthreads();
    int wbase = (wid > 0) ? wsum[wid - 1] : 0;
    if (i < n) offs[i + 1] = wbase + x;
    if (threadIdx.x == 1023) part[b] = wsum[15];
}

// stage 2: add exclusive prefix of part[] to each block's region (nb <= 64)
__launch_bounds__(1024)
__global__ void k_scan2(int* __restrict__ offs, const int* __restrict__ part, int n) {
    __shared__ int sprefix;
    int b = blockIdx.x;
    if (threadIdx.x < 64) {
        int p = ((int)threadIdx.x < b) ? part[threadIdx.x] : 0;
#pragma unroll
        for (int s = 32; s; s >>= 1) p += __shfl_down(p, s);
        if (threadIdx.x == 0) sprefix = p;
    }
    __syncthreads();
    int i = b * 1024 + (int)threadIdx.x;
    if (i < n) offs[i + 1] += sprefix;
    if (b == 0 && threadIdx.x == 0) offs[0] = 0;
}

// scatter with inline rsqrt normalization; CSR record packed as int2{src, w}
__global__ void k_scatter(const int* __restrict__ src, const int* __restrict__ dst,
                          const float* __restrict__ ew, const float* __restrict__ deg,
                          const int* __restrict__ offs, int* cur,
                          int2* __restrict__ csr, int e) {
    int i = blockIdx.x * blockDim.x + threadIdx.x;
    if (i < e) {
        int s = src[i], d = dst[i];
        float ds_ = deg[s], dd = deg[d];
        float rs = ds_ > 0.f ? rsqrtf(fmaxf(ds_, 1e-12f)) : 0.f;
        float rd = dd > 0.f ? rsqrtf(fmaxf(dd, 1e-12f)) : 0.f;
        float wn = -rs * ew[i] * rd;
        int pos = offs[d] + atomicAdd(&cur[d], 1);
        csr[pos] = make_int2(s, __float_as_int(wn));
    }
}

// ---------------- pack kernels ----------------

// A[n][0:256]=bf16(x), A[n][256:512]=bf16(h)
__global__ void k_packA(const float* __restrict__ x, const float* __restrict__ h,
                        unsigned short* __restrict__ A, int n) {
    int t = blockIdx.x * blockDim.x + threadIdx.x;
    int node = t >> 6, q = t & 63;
    if (node >= n) return;
    floatx4 xv = *(const floatx4*)(x + (size_t)node * FDIM + q * 4);
    floatx4 hv = *(const floatx4*)(h + (size_t)node * FDIM + q * 4);
    ushort4 ox, oh;
    ox.x = f2bf(xv[0]); ox.y = f2bf(xv[1]); ox.z = f2bf(xv[2]); ox.w = f2bf(xv[3]);
    oh.x = f2bf(hv[0]); oh.y = f2bf(hv[1]); oh.z = f2bf(hv[2]); oh.w = f2bf(hv[3]);
    *(ushort4*)(A + (size_t)node * KDIM + q * 4) = ox;
    *(ushort4*)(A + (size_t)node * KDIM + FDIM + q * 4) = oh;
}

// Gate-interleaved packed B^T.
// packed col p: group=p>>6, gate=(p>>4)&3, feat=(group<<4)|(p&15)
// row r: kb=r>>8 selects {W, theta0, theta1, theta2}, rr=r&255
__global__ void k_packBt(const float* __restrict__ W, const float* __restrict__ theta,
                         unsigned short* __restrict__ Bt) {
    int t = blockIdx.x * blockDim.x + threadIdx.x; // over 1024*1024
    int p = t >> 10, r = t & 1023;
    int group = p >> 6, gate = (p >> 4) & 3;
    int feat = (group << 4) | (p & 15);
    int kb = r >> 8, rr = r & 255;
    float v;
    if (kb == 0) v = W[((size_t)(gate * FDIM + rr)) * FDIM + feat];
    else         v = theta[((size_t)((gate * 3 + (kb - 1)) * FDIM + rr)) * FDIM + feat];
    Bt[t] = f2bf(v);
}

// ---------------- sparse prop (CSR gather, wave per node, 2 half-waves x 4 unroll) ----------------

// Tx1 = prop(h): gather bf16 h from A[:,256:512], write bf16 to A[:,512:768]
__launch_bounds__(256)
__global__ void k_prop1(unsigned short* __restrict__ A, const int* __restrict__ offs,
                        const int2* __restrict__ csr, int n) {
    int wid = (blockIdx.x * blockDim.x + threadIdx.x) >> 6;
    int lane = threadIdx.x & 63;
    if (wid >= n) return;
    int half = lane >> 5, l = lane & 31;
    int beg = offs[wid], end = offs[wid + 1];
    float a[8] = {0.f, 0.f, 0.f, 0.f, 0.f, 0.f, 0.f, 0.f};
    int j = beg + half;
    for (; j + 6 < end; j += 8) {
        int2 e0 = csr[j], e1 = csr[j + 2], e2 = csr[j + 4], e3 = csr[j + 6];
        short8 v0 = *(const short8*)(A + (size_t)e0.x * KDIM + FDIM + l * 8);
        short8 v1 = *(const short8*)(A + (size_t)e1.x * KDIM + FDIM + l * 8);
        short8 v2 = *(const short8*)(A + (size_t)e2.x * KDIM + FDIM + l * 8);
        short8 v3 = *(const short8*)(A + (size_t)e3.x * KDIM + FDIM + l * 8);
        float w0 = __int_as_float(e0.y), w1 = __int_as_float(e1.y);
        float w2 = __int_as_float(e2.y), w3 = __int_as_float(e3.y);
#pragma unroll
        for (int k = 0; k < 8; ++k)
            a[k] += w0 * bf2f((unsigned short)v0[k]) + w1 * bf2f((unsigned short)v1[k])
                  + w2 * bf2f((unsigned short)v2[k]) + w3 * bf2f((unsigned short)v3[k]);
    }
    for (; j < end; j += 2) {
        int2 e0 = csr[j];
        float w0 = __int_as_float(e0.y);
        short8 v0 = *(const short8*)(A + (size_t)e0.x * KDIM + FDIM + l * 8);
#pragma unroll
        for (int k = 0; k < 8; ++k) a[k] += w0 * bf2f((unsigned short)v0[k]);
    }
#pragma unroll
    for (int k = 0; k < 8; ++k) a[k] += __shfl_xor(a[k], 32);
    if (half == 0) {
        short8 o;
#pragma unroll
        for (int k = 0; k < 8; ++k) o[k] = (short)f2bf(a[k]);
        *(short8*)(A + (size_t)wid * KDIM + 2 * FDIM + l * 8) = o;
    }
}

// Tx2 = 2*prop(Tx1) - h
__launch_bounds__(256)
__global__ void k_prop2(unsigned short* __restrict__ A, const float* __restrict__ h,
                        const int* __restrict__ offs, const int2* __restrict__ csr, int n) {
    int wid = (blockIdx.x * blockDim.x + threadIdx.x) >> 6;
    int lane = threadIdx.x & 63;
    if (wid >= n) return;
    int half = lane >> 5, l = lane & 31;
    int beg = offs[wid], end = offs[wid + 1];
    float a[8] = {0.f, 0.f, 0.f, 0.f, 0.f, 0.f, 0.f, 0.f};
    int j = beg + half;
    for (; j + 6 < end; j += 8) {
        int2 e0 = csr[j], e1 = csr[j + 2], e2 = csr[j + 4], e3 = csr[j + 6];
        short8 v0 = *(const short8*)(A + (size_t)e0.x * KDIM + 2 * FDIM + l * 8);
        short8 v1 = *(const short8*)(A + (size_t)e1.x * KDIM + 2 * FDIM + l * 8);
        short8 v2 = *(const short8*)(A + (size_t)e2.x * KDIM + 2 * FDIM + l * 8);
        short8 v3 = *(const short8*)(A + (size_t)e3.x * KDIM + 2 * FDIM + l * 8);
        float w0 = __int_as_float(e0.y), w1 = __int_as_float(e1.y);
        float w2 = __int_as_float(e2.y), w3 = __int_as_float(e3.y);
#pragma unroll
        for (int k = 0; k < 8; ++k)
            a[k] += w0 * bf2f((unsigned short)v0[k]) + w1 * bf2f((unsigned short)v1[k])
                  + w2 * bf2f((unsigned short)v2[k]) + w3 * bf2f((unsigned short)v3[k]);
    }
    for (; j < end; j += 2) {
        int2 e0 = csr[j];
        float w0 = __int_as_float(e0.y);
        short8 v0 = *(const short8*)(A + (size_t)e0.x * KDIM + 2 * FDIM + l * 8);
#pragma unroll
        for (int k = 0; k < 8; ++k) a[k] += w0 * bf2f((unsigned short)v0[k]);
    }
#pragma unroll
    for (int k = 0; k < 8; ++k) a[k] += __shfl_xor(a[k], 32);
    if (half == 0) {
        floatx4 hv0 = *(const floatx4*)(h + (size_t)wid * FDIM + l * 8);
        floatx4 hv1 = *(const floatx4*)(h + (size_t)wid * FDIM + l * 8 + 4);
        short8 o;
#pragma unroll
        for (int k = 0; k < 4; ++k) o[k] = (short)f2bf(2.f * a[k] - hv0[k]);
#pragma unroll
        for (int k = 0; k < 4; ++k) o[4 + k] = (short)f2bf(2.f * a[4 + k] - hv1[k]);
        *(short8*)(A + (size_t)wid * KDIM + 3 * FDIM + l * 8) = o;
    }
}

// ---------------- GEMM + fused LSTM epilogue ----------------
// BK=64, XOR-swizzled LDS, DOUBLE-BUFFERED with counted vmcnt (T3/T4):
// prefetch next tile's 8 global_load_lds before computing current; wait vmcnt(8)
// (not 0) so prefetch stays in flight across the raw s_barrier.

__launch_bounds__(256, 2)
__global__ void k_gemm(const unsigned short* __restrict__ A, const unsigned short* __restrict__ Bt,
                       const float* __restrict__ c, const float* __restrict__ b_conv,
                       const float* __restrict__ b, const float* __restrict__ w_c,
                       const float* __restrict__ Wcls,
                       float* __restrict__ out_h, float* __restrict__ out_c,
                       float* __restrict__ cls_part, int M, int mtiles) {
    __shared__ unsigned short sA[2][128 * 64];
    __shared__ unsigned short sB[2][128 * 64];
    int tid = threadIdx.x;
    int lane = tid & 63;
    int w = tid >> 6;
    // XCD-aware swizzle: 8 consecutive nt-blocks (one A panel) land on one XCD chunk
    int nb = mtiles * 8;
    int bid = blockIdx.x;
    int wg = (bid & 7) * (nb >> 3) + (bid >> 3);
    int mt = wg >> 3;
    int nt = wg & 7;
    int brow = mt * 128, bcol = nt * 128;
    int wr = (w >> 1) * 64, wc = (w & 1) * 64;
    int l15 = lane & 15, l4 = lane >> 4;

    auto STAGE = [&](int kt, int bufi) {
        int k0 = kt * 64;
#pragma unroll
        for (int p = 0; p < 4; ++p) {
            int cch = tid + p * 256;            // 0..1023 chunks of 16B
            int row = cch >> 3, cslot = cch & 7;
            int csrc = cslot ^ (row & 7);       // inverse-swizzled source chunk
            int grow = brow + row; if (grow >= M) grow = M - 1;
            const unsigned short* g = A + (size_t)grow * KDIM + k0 + csrc * 8;
            __builtin_amdgcn_global_load_lds((const GLOBAL_AS void*)g,
                                             (LDS_AS void*)(sA[bufi] + cch * 8), 16, 0, 0);
        }
#pragma unroll
        for (int p = 0; p < 4; ++p) {
            int cch = tid + p * 256;
            int row = cch >> 3, cslot = cch & 7;
            int csrc = cslot ^ (row & 7);
            const unsigned short* g = Bt + (size_t)(bcol + row) * KDIM + k0 + csrc * 8;
            __builtin_amdgcn_global_load_lds((const GLOBAL_AS void*)g,
                                             (LDS_AS void*)(sB[bufi] + cch * 8), 16, 0, 0);
        }
    };

    floatx4 acc[4][4];
#pragma unroll
    for (int m = 0; m < 4; ++m)
#pragma unroll
        for (int g = 0; g < 4; ++g)
            acc[m][g] = (floatx4){0.f, 0.f, 0.f, 0.f};

    STAGE(0, 0);   // prologue

    for (int kt = 0; kt < 16; ++kt) {
        int cur = kt & 1;
        if (kt < 15) {
            STAGE(kt + 1, cur ^ 1);
            // wait current tile's 8 loads; leave prefetch (8) in flight
            asm volatile("s_waitcnt vmcnt(8)" ::: "memory");
        } else {
            asm volatile("s_waitcnt vmcnt(0)" ::: "memory");
        }
        __builtin_amdgcn_s_barrier();
        __builtin_amdgcn_sched_barrier(0);

#pragma unroll
        for (int ks = 0; ks < 2; ++ks) {
            short8 af[4], bfr[4];
#pragma unroll
            for (int m = 0; m < 4; ++m) {
                int ra = wr + m * 16 + l15;
                af[m] = *(const short8*)(sA[cur] + ra * 64 + ((ks * 4 + l4) ^ (ra & 7)) * 8);
            }
#pragma unroll
            for (int g = 0; g < 4; ++g) {
                int rb = wc + g * 16 + l15;
                bfr[g] = *(const short8*)(sB[cur] + rb * 64 + ((ks * 4 + l4) ^ (rb & 7)) * 8);
            }
#pragma unroll
            for (int m = 0; m < 4; ++m)
#pragma unroll
                for (int g = 0; g < 4; ++g)
                    acc[m][g] = __builtin_amdgcn_mfma_f32_16x16x32_bf16(af[m], bfr[g], acc[m][g], 0, 0, 0);
        }
        // ensure this wave's LDS reads are complete before any wave re-stages this buffer
        asm volatile("s_waitcnt lgkmcnt(0)" ::: "memory");
        __builtin_amdgcn_sched_barrier(0);
        __builtin_amdgcn_s_barrier();
    }

    // fused epilogue: this wave owns feature-group `group` for its 128-row slice
    int group = (bcol + wc) >> 6;          // 0..15
    int feat = (group << 4) | l15;         // 0..255
    float bc0 = b_conv[feat], bc1 = b_conv[FDIM + feat];
    float bc2 = b_conv[2 * FDIM + feat], bc3 = b_conv[3 * FDIM + feat];
    float bb0 = b[feat], bb1 = b[FDIM + feat];
    float bb2 = b[2 * FDIM + feat], bb3 = b[3 * FDIM + feat];
    float wci = w_c[feat], wcf = w_c[FDIM + feat], wco = w_c[2 * FDIM + feat];
    float wcl = Wcls[feat];

#pragma unroll
    for (int m = 0; m < 4; ++m) {
#pragma unroll
        for (int j = 0; j < 4; ++j) {
            int node = brow + wr + m * 16 + l4 * 4 + j;
            bool ok = node < M;
            int nidx = ok ? node : (M - 1);
            float cv = c[(size_t)nidx * FDIM + feat];
            float iv = sig(acc[m][0][j] + bc0 + wci * cv + bb0);
            float fv = sig(acc[m][1][j] + bc1 + wcf * cv + bb1);
            float tv = tanhf(acc[m][2][j] + bc2 + bb2);
            float cn = fv * cv + iv * tv;
            float ov = sig(acc[m][3][j] + bc3 + wco * cn + bb3);
            float hn = ov * tanhf(cn);
            if (ok) {
                out_h[(size_t)node * FDIM + feat] = hn;
                out_c[(size_t)node * FDIM + feat] = cn;
            }
            float pcls = fmaxf(hn, 0.f) * wcl;
#pragma unroll
            for (int s = 1; s < 16; s <<= 1) pcls += __shfl_xor(pcls, s);
            if (ok && l15 == 0) cls_part[(size_t)node * 16 + group] = pcls;
        }
    }
}

// classifier partial reduce: out_cls[i] = sum_g cls_part[i][g] + b_cls
__global__ void k_cls(const float* __restrict__ cls_part, const float* __restrict__ bcls,
                      float* __restrict__ out_cls, int n) {
    int i = blockIdx.x * blockDim.x + threadIdx.x;
    if (i >= n) return;
    const floatx4* p = (const floatx4*)(cls_part + (size_t)i * 16);
    floatx4 v0 = p[0], v1 = p[1], v2 = p[2], v3 = p[3];
    float s = v0[0] + v0[1] + v0[2] + v0[3] + v1[0] + v1[1] + v1[2] + v1[3]
            + v2[0] + v2[1] + v2[2] + v2[3] + v3[0] + v3[1] + v3[2] + v3[3];
    out_cls[i] = s + bcls[0];
}

// ---------------- launcher ----------------

extern "C" void kernel_launch(void* const* d_in, const int* in_sizes, int n_in,
                              void* d_out, int out_size, void* d_ws, size_t ws_size,
                              hipStream_t stream) {
    const float* x      = (const float*)d_in[0];
    const int*   eidx   = (const int*)d_in[1];
    const float* ew     = (const float*)d_in[2];
    const float* h      = (const float*)d_in[3];
    const float* c      = (const float*)d_in[4];
    const float* W      = (const float*)d_in[5];
    const float* theta  = (const float*)d_in[6];
    const float* b_conv = (const float*)d_in[7];
    const float* b      = (const float*)d_in[8];
    const float* w_c    = (const float*)d_in[9];
    const float* Wcls   = (const float*)d_in[10];
    const float* bcls   = (const float*)d_in[11];

    const int N = in_sizes[0] / FDIM;
    const int E = in_sizes[2];
    const int* src = eidx;
    const int* dst = eidx + E;

    char* ws = (char*)d_ws;
    size_t off = 0;
    auto alloc = [&](size_t bytes) -> void* {
        void* p = ws + off;
        off += (bytes + 255) & ~(size_t)255;
        return p;
    };
    unsigned short* A   = (unsigned short*)alloc((size_t)N * KDIM * 2);
    unsigned short* Bt  = (unsigned short*)alloc((size_t)KDIM * KDIM * 2);
    float* cls_part     = (float*)alloc((size_t)N * 16 * 4);
    float* deg          = (float*)alloc((size_t)N * 4);
    int*   cnt          = (int*)alloc((size_t)N * 4);
    int*   cur          = (int*)alloc((size_t)N * 4);
    int*   offs         = (int*)alloc((size_t)(N + 1) * 4);
    int*   part         = (int*)alloc(64 * 4);
    int2*  csr          = (int2*)alloc((size_t)E * 8);
    (void)ws_size; (void)n_in; (void)out_size;

    float* out_cls = (float*)d_out;
    float* out_h   = out_cls + N;
    float* out_c   = out_h + (size_t)N * FDIM;

    // zero deg/cnt/cur in one async memset (consecutive allocs)
    size_t zbytes = (size_t)((char*)(cur + N) - (char*)deg);
    hipMemsetAsync(deg, 0, zbytes, stream);

    int nsb = (N + 1023) / 1024;  // <= 64
    k_degcnt<<<(E + 255) / 256, 256, 0, stream>>>(src, dst, ew, deg, cnt, E);
    k_scan1<<<nsb, 1024, 0, stream>>>(cnt, offs, part, N);
    k_scan2<<<nsb, 1024, 0, stream>>>(offs, part, N);
    k_scatter<<<(E + 255) / 256, 256, 0, stream>>>(src, dst, ew, deg, offs, cur, csr, E);
    k_packA<<<(N * 64 + 255) / 256, 256, 0, stream>>>(x, h, A, N);
    k_packBt<<<(KDIM * KDIM + 255) / 256, 256, 0, stream>>>(W, theta, Bt);
    k_prop1<<<(N * 64 + 255) / 256, 256, 0, stream>>>(A, offs, csr, N);
    k_prop2<<<(N * 64 + 255) / 256, 256, 0, stream>>>(A, h, offs, csr, N);
    int mtiles = (N + 127) / 128;
    k_gemm<<<mtiles * 8, 256, 0, stream>>>(A, Bt, c, b_conv, b, w_c, Wcls,
                                           out_h, out_c, cls_part, N, mtiles);
    k_cls<<<(N + 255) / 256, 256, 0, stream>>>(cls_part, bcls, out_cls, N);
}

// Round 5
// 200.000 us; speedup vs baseline: 1.0587x; 1.0587x over previous
//
#include <hip/hip_runtime.h>
#include <stdint.h>

#define FDIM 256
#define KDIM 1024   // 4*F : [x | h | Tx1 | Tx2]

typedef __attribute__((ext_vector_type(8))) short short8;
typedef __attribute__((ext_vector_type(4))) float floatx4;

#define GLOBAL_AS __attribute__((address_space(1)))
#define LDS_AS    __attribute__((address_space(3)))

static __device__ __forceinline__ unsigned short f2bf(float f) {
    unsigned int u = __float_as_uint(f);
    unsigned int r = (u + 0x7FFFu + ((u >> 16) & 1u)) >> 16;
    return (unsigned short)r;
}
static __device__ __forceinline__ float bf2f(unsigned short s) {
    return __uint_as_float(((unsigned int)s) << 16);
}
static __device__ __forceinline__ float sig(float x) {
    return 1.f / (1.f + __expf(-x));
}

// ---------------- setup kernels ----------------

__global__ void k_degcnt(const int* __restrict__ src, const int* __restrict__ dst,
                         const float* __restrict__ ew, float* deg, int* cnt, int e) {
    int i = blockIdx.x * blockDim.x + threadIdx.x;
    if (i < e) {
        atomicAdd(&deg[src[i]], ew[i]);
        atomicAdd(&cnt[dst[i]], 1);
    }
}

// hierarchical scan, stage 1: per-1024-block inclusive scan -> offs[i+1], block total -> part[b]
__launch_bounds__(1024)
__global__ void k_scan1(const int* __restrict__ cnt, int* __restrict__ offs,
                        int* __restrict__ part, int n) {
    __shared__ int wsum[16];
    int b = blockIdx.x;
    int i = b * 1024 + (int)threadIdx.x;
    int lane = threadIdx.x & 63;
    int wid = threadIdx.x >> 6;
    int x = (i < n) ? cnt[i] : 0;
#pragma unroll
    for (int s = 1; s < 64; s <<= 1) {
        int t = __shfl_up(x, s);
        if (lane >= s) x += t;
    }
    if (lane == 63) wsum[wid] = x;
    __syncthreads();
    if (wid == 0) {
        int y = (lane < 16) ? wsum[lane] : 0;
#pragma unroll
        for (int s = 1; s < 16; s <<= 1) {
            int t = __shfl_up(y, s);
            if (lane >= s) y += t;
        }
        if (lane < 16) wsum[lane] = y;
    }
    __syncthreads();
    int wbase = (wid > 0) ? wsum[wid - 1] : 0;
    if (i < n) offs[i + 1] = wbase + x;
    if (threadIdx.x == 1023) part[b] = wsum[15];
}

// stage 2: add exclusive prefix of part[] to each block's region (nb <= 64)
__launch_bounds__(1024)
__global__ void k_scan2(int* __restrict__ offs, const int* __restrict__ part, int n) {
    __shared__ int sprefix;
    int b = blockIdx.x;
    if (threadIdx.x < 64) {
        int p = ((int)threadIdx.x < b) ? part[threadIdx.x] : 0;
#pragma unroll
        for (int s = 32; s; s >>= 1) p += __shfl_down(p, s);
        if (threadIdx.x == 0) sprefix = p;
    }
    __syncthreads();
    int i = b * 1024 + (int)threadIdx.x;
    if (i < n) offs[i + 1] += sprefix;
    if (b == 0 && threadIdx.x == 0) offs[0] = 0;
}

// scatter with inline rsqrt normalization; CSR record packed as int2{src, w}
__global__ void k_scatter(const int* __restrict__ src, const int* __restrict__ dst,
                          const float* __restrict__ ew, const float* __restrict__ deg,
                          const int* __restrict__ offs, int* cur,
                          int2* __restrict__ csr, int e) {
    int i = blockIdx.x * blockDim.x + threadIdx.x;
    if (i < e) {
        int s = src[i], d = dst[i];
        float ds_ = deg[s], dd = deg[d];
        float rs = ds_ > 0.f ? rsqrtf(fmaxf(ds_, 1e-12f)) : 0.f;
        float rd = dd > 0.f ? rsqrtf(fmaxf(dd, 1e-12f)) : 0.f;
        float wn = -rs * ew[i] * rd;
        int pos = offs[d] + atomicAdd(&cur[d], 1);
        csr[pos] = make_int2(s, __float_as_int(wn));
    }
}

// ---------------- pack kernels ----------------

// A[n][0:256]=bf16(x), A[n][256:512]=bf16(h)
__global__ void k_packA(const float* __restrict__ x, const float* __restrict__ h,
                        unsigned short* __restrict__ A, int n) {
    int t = blockIdx.x * blockDim.x + threadIdx.x;
    int node = t >> 6, q = t & 63;
    if (node >= n) return;
    floatx4 xv = *(const floatx4*)(x + (size_t)node * FDIM + q * 4);
    floatx4 hv = *(const floatx4*)(h + (size_t)node * FDIM + q * 4);
    ushort4 ox, oh;
    ox.x = f2bf(xv[0]); ox.y = f2bf(xv[1]); ox.z = f2bf(xv[2]); ox.w = f2bf(xv[3]);
    oh.x = f2bf(hv[0]); oh.y = f2bf(hv[1]); oh.z = f2bf(hv[2]); oh.w = f2bf(hv[3]);
    *(ushort4*)(A + (size_t)node * KDIM + q * 4) = ox;
    *(ushort4*)(A + (size_t)node * KDIM + FDIM + q * 4) = oh;
}

// Fragment-major packed B (direct MFMA B-operand layout, read from L2 — no LDS):
// element index = ((pg*32 + kt*2 + ks)*64 + lane)*8 + e
// maps to packed col p = pg*16 + (lane&15), k-row r = kt*64 + ks*32 + (lane>>4)*8 + e.
// packed col p: group=p>>6, gate=(p>>4)&3, feat=(group<<4)|(p&15)
// k-row r: kb=r>>8 selects {W, theta0, theta1, theta2}, rr=r&255
__global__ void k_packBt(const float* __restrict__ W, const float* __restrict__ theta,
                         unsigned short* __restrict__ Bt) {
    int t = blockIdx.x * blockDim.x + threadIdx.x; // over 1024*1024
    int e = t & 7;
    int lane = (t >> 3) & 63;
    int ks = (t >> 9) & 1;
    int kt = (t >> 10) & 15;
    int pg = t >> 14;
    int p = pg * 16 + (lane & 15);
    int r = kt * 64 + ks * 32 + (lane >> 4) * 8 + e;
    int group = p >> 6, gate = (p >> 4) & 3;
    int feat = (group << 4) | (p & 15);
    int kb = r >> 8, rr = r & 255;
    float v;
    if (kb == 0) v = W[((size_t)(gate * FDIM + rr)) * FDIM + feat];
    else         v = theta[((size_t)((gate * 3 + (kb - 1)) * FDIM + rr)) * FDIM + feat];
    Bt[t] = f2bf(v);
}

// ---------------- sparse prop (CSR gather, wave per node, 2 half-waves x 4 unroll) ----------------

// Tx1 = prop(h): gather bf16 h from A[:,256:512], write bf16 to A[:,512:768]
__launch_bounds__(256)
__global__ void k_prop1(unsigned short* __restrict__ A, const int* __restrict__ offs,
                        const int2* __restrict__ csr, int n) {
    int wid = (blockIdx.x * blockDim.x + threadIdx.x) >> 6;
    int lane = threadIdx.x & 63;
    if (wid >= n) return;
    int half = lane >> 5, l = lane & 31;
    int beg = offs[wid], end = offs[wid + 1];
    float a[8] = {0.f, 0.f, 0.f, 0.f, 0.f, 0.f, 0.f, 0.f};
    int j = beg + half;
    for (; j + 6 < end; j += 8) {
        int2 e0 = csr[j], e1 = csr[j + 2], e2 = csr[j + 4], e3 = csr[j + 6];
        short8 v0 = *(const short8*)(A + (size_t)e0.x * KDIM + FDIM + l * 8);
        short8 v1 = *(const short8*)(A + (size_t)e1.x * KDIM + FDIM + l * 8);
        short8 v2 = *(const short8*)(A + (size_t)e2.x * KDIM + FDIM + l * 8);
        short8 v3 = *(const short8*)(A + (size_t)e3.x * KDIM + FDIM + l * 8);
        float w0 = __int_as_float(e0.y), w1 = __int_as_float(e1.y);
        float w2 = __int_as_float(e2.y), w3 = __int_as_float(e3.y);
#pragma unroll
        for (int k = 0; k < 8; ++k)
            a[k] += w0 * bf2f((unsigned short)v0[k]) + w1 * bf2f((unsigned short)v1[k])
                  + w2 * bf2f((unsigned short)v2[k]) + w3 * bf2f((unsigned short)v3[k]);
    }
    for (; j < end; j += 2) {
        int2 e0 = csr[j];
        float w0 = __int_as_float(e0.y);
        short8 v0 = *(const short8*)(A + (size_t)e0.x * KDIM + FDIM + l * 8);
#pragma unroll
        for (int k = 0; k < 8; ++k) a[k] += w0 * bf2f((unsigned short)v0[k]);
    }
#pragma unroll
    for (int k = 0; k < 8; ++k) a[k] += __shfl_xor(a[k], 32);
    if (half == 0) {
        short8 o;
#pragma unroll
        for (int k = 0; k < 8; ++k) o[k] = (short)f2bf(a[k]);
        *(short8*)(A + (size_t)wid * KDIM + 2 * FDIM + l * 8) = o;
    }
}

// Tx2 = 2*prop(Tx1) - h
__launch_bounds__(256)
__global__ void k_prop2(unsigned short* __restrict__ A, const float* __restrict__ h,
                        const int* __restrict__ offs, const int2* __restrict__ csr, int n) {
    int wid = (blockIdx.x * blockDim.x + threadIdx.x) >> 6;
    int lane = threadIdx.x & 63;
    if (wid >= n) return;
    int half = lane >> 5, l = lane & 31;
    int beg = offs[wid], end = offs[wid + 1];
    float a[8] = {0.f, 0.f, 0.f, 0.f, 0.f, 0.f, 0.f, 0.f};
    int j = beg + half;
    for (; j + 6 < end; j += 8) {
        int2 e0 = csr[j], e1 = csr[j + 2], e2 = csr[j + 4], e3 = csr[j + 6];
        short8 v0 = *(const short8*)(A + (size_t)e0.x * KDIM + 2 * FDIM + l * 8);
        short8 v1 = *(const short8*)(A + (size_t)e1.x * KDIM + 2 * FDIM + l * 8);
        short8 v2 = *(const short8*)(A + (size_t)e2.x * KDIM + 2 * FDIM + l * 8);
        short8 v3 = *(const short8*)(A + (size_t)e3.x * KDIM + 2 * FDIM + l * 8);
        float w0 = __int_as_float(e0.y), w1 = __int_as_float(e1.y);
        float w2 = __int_as_float(e2.y), w3 = __int_as_float(e3.y);
#pragma unroll
        for (int k = 0; k < 8; ++k)
            a[k] += w0 * bf2f((unsigned short)v0[k]) + w1 * bf2f((unsigned short)v1[k])
                  + w2 * bf2f((unsigned short)v2[k]) + w3 * bf2f((unsigned short)v3[k]);
    }
    for (; j < end; j += 2) {
        int2 e0 = csr[j];
        float w0 = __int_as_float(e0.y);
        short8 v0 = *(const short8*)(A + (size_t)e0.x * KDIM + 2 * FDIM + l * 8);
#pragma unroll
        for (int k = 0; k < 8; ++k) a[k] += w0 * bf2f((unsigned short)v0[k]);
    }
#pragma unroll
    for (int k = 0; k < 8; ++k) a[k] += __shfl_xor(a[k], 32);
    if (half == 0) {
        floatx4 hv0 = *(const floatx4*)(h + (size_t)wid * FDIM + l * 8);
        floatx4 hv1 = *(const floatx4*)(h + (size_t)wid * FDIM + l * 8 + 4);
        short8 o;
#pragma unroll
        for (int k = 0; k < 4; ++k) o[k] = (short)f2bf(2.f * a[k] - hv0[k]);
#pragma unroll
        for (int k = 0; k < 4; ++k) o[4 + k] = (short)f2bf(2.f * a[4 + k] - hv1[k]);
        *(short8*)(A + (size_t)wid * KDIM + 3 * FDIM + l * 8) = o;
    }
}

// ---------------- GEMM + fused LSTM epilogue ----------------
// A: swizzled LDS, double-buffered (2x16 KiB), ONE __syncthreads per K-iter;
// prefetch of tile kt+1 issued right after the barrier, drained at the NEXT
// barrier (a full compute phase later) -> staging latency hidden, no inline asm.
// B: fragment-major in global, read as coalesced 1KB/wave dwordx4 from L2 (no LDS).

__launch_bounds__(256, 3)
__global__ void k_gemm(const unsigned short* __restrict__ A, const unsigned short* __restrict__ Bf,
                       const float* __restrict__ c, const float* __restrict__ b_conv,
                       const float* __restrict__ b, const float* __restrict__ w_c,
                       const float* __restrict__ Wcls,
                       float* __restrict__ out_h, float* __restrict__ out_c,
                       float* __restrict__ cls_part, int M, int mtiles) {
    __shared__ unsigned short sA[2][128 * 64];
    int tid = threadIdx.x;
    int lane = tid & 63;
    int w = tid >> 6;
    // XCD-aware swizzle: 8 consecutive nt-blocks (one A panel) land on one XCD chunk
    int nb = mtiles * 8;
    int bid = blockIdx.x;
    int wg = (bid & 7) * (nb >> 3) + (bid >> 3);
    int mt = wg >> 3;
    int nt = wg & 7;
    int brow = mt * 128, bcol = nt * 128;
    int wr = (w >> 1) * 64, wc = (w & 1) * 64;
    int l15 = lane & 15, l4 = lane >> 4;

    // this wave's packed-col-group base (4 groups of 16 cols = 4 gates x 16 feats)
    int pgbase = nt * 8 + (w & 1) * 4;
    const unsigned short* Bwave = Bf + (size_t)pgbase * 32 * 64 * 8;

    auto STAGE_A = [&](int kt, int bufi) {
        int k0 = kt * 64;
#pragma unroll
        for (int p = 0; p < 4; ++p) {
            int cch = tid + p * 256;            // 0..1023 chunks of 16B
            int row = cch >> 3, cslot = cch & 7;
            int csrc = cslot ^ (row & 7);       // inverse-swizzled source chunk
            int grow = brow + row; if (grow >= M) grow = M - 1;
            const unsigned short* g = A + (size_t)grow * KDIM + k0 + csrc * 8;
            __builtin_amdgcn_global_load_lds((const GLOBAL_AS void*)g,
                                             (LDS_AS void*)(sA[bufi] + cch * 8), 16, 0, 0);
        }
    };

    floatx4 acc[4][4];
#pragma unroll
    for (int m = 0; m < 4; ++m)
#pragma unroll
        for (int g = 0; g < 4; ++g)
            acc[m][g] = (floatx4){0.f, 0.f, 0.f, 0.f};

    STAGE_A(0, 0);   // prologue

    for (int kt = 0; kt < 16; ++kt) {
        int cur = kt & 1;
        __syncthreads();                    // drains staging of sA[cur]; prev reads done
        if (kt < 15) STAGE_A(kt + 1, cur ^ 1);  // prefetch; drained at NEXT barrier

        // B fragments for this K-tile: 8 coalesced 16B/lane loads (L2-resident)
        short8 bfr[2][4];
#pragma unroll
        for (int ks = 0; ks < 2; ++ks)
#pragma unroll
            for (int g = 0; g < 4; ++g)
                bfr[ks][g] = *(const short8*)(Bwave +
                    (size_t)(((g * 32 + kt * 2 + ks) * 64) + lane) * 8);

#pragma unroll
        for (int ks = 0; ks < 2; ++ks) {
            short8 af[4];
#pragma unroll
            for (int m = 0; m < 4; ++m) {
                int ra = wr + m * 16 + l15;
                af[m] = *(const short8*)(sA[cur] + ra * 64 + ((ks * 4 + l4) ^ (ra & 7)) * 8);
            }
#pragma unroll
            for (int m = 0; m < 4; ++m)
#pragma unroll
                for (int g = 0; g < 4; ++g)
                    acc[m][g] = __builtin_amdgcn_mfma_f32_16x16x32_bf16(af[m], bfr[ks][g], acc[m][g], 0, 0, 0);
        }
    }

    // fused epilogue: this wave owns feature-group `group` for its 128-row slice
    int group = (bcol + wc) >> 6;          // 0..15
    int feat = (group << 4) | l15;         // 0..255
    float bc0 = b_conv[feat], bc1 = b_conv[FDIM + feat];
    float bc2 = b_conv[2 * FDIM + feat], bc3 = b_conv[3 * FDIM + feat];
    float bb0 = b[feat], bb1 = b[FDIM + feat];
    float bb2 = b[2 * FDIM + feat], bb3 = b[3 * FDIM + feat];
    float wci = w_c[feat], wcf = w_c[FDIM + feat], wco = w_c[2 * FDIM + feat];
    float wcl = Wcls[feat];

#pragma unroll
    for (int m = 0; m < 4; ++m) {
#pragma unroll
        for (int j = 0; j < 4; ++j) {
            int node = brow + wr + m * 16 + l4 * 4 + j;
            bool ok = node < M;
            int nidx = ok ? node : (M - 1);
            float cv = c[(size_t)nidx * FDIM + feat];
            float iv = sig(acc[m][0][j] + bc0 + wci * cv + bb0);
            float fv = sig(acc[m][1][j] + bc1 + wcf * cv + bb1);
            float tv = tanhf(acc[m][2][j] + bc2 + bb2);
            float cn = fv * cv + iv * tv;
            float ov = sig(acc[m][3][j] + bc3 + wco * cn + bb3);
            float hn = ov * tanhf(cn);
            if (ok) {
                out_h[(size_t)node * FDIM + feat] = hn;
                out_c[(size_t)node * FDIM + feat] = cn;
            }
            float pcls = fmaxf(hn, 0.f) * wcl;
#pragma unroll
            for (int s = 1; s < 16; s <<= 1) pcls += __shfl_xor(pcls, s);
            if (ok && l15 == 0) cls_part[(size_t)node * 16 + group] = pcls;
        }
    }
}

// classifier partial reduce: out_cls[i] = sum_g cls_part[i][g] + b_cls
__global__ void k_cls(const float* __restrict__ cls_part, const float* __restrict__ bcls,
                      float* __restrict__ out_cls, int n) {
    int i = blockIdx.x * blockDim.x + threadIdx.x;
    if (i >= n) return;
    const floatx4* p = (const floatx4*)(cls_part + (size_t)i * 16);
    floatx4 v0 = p[0], v1 = p[1], v2 = p[2], v3 = p[3];
    float s = v0[0] + v0[1] + v0[2] + v0[3] + v1[0] + v1[1] + v1[2] + v1[3]
            + v2[0] + v2[1] + v2[2] + v2[3] + v3[0] + v3[1] + v3[2] + v3[3];
    out_cls[i] = s + bcls[0];
}

// ---------------- launcher ----------------

extern "C" void kernel_launch(void* const* d_in, const int* in_sizes, int n_in,
                              void* d_out, int out_size, void* d_ws, size_t ws_size,
                              hipStream_t stream) {
    const float* x      = (const float*)d_in[0];
    const int*   eidx   = (const int*)d_in[1];
    const float* ew     = (const float*)d_in[2];
    const float* h      = (const float*)d_in[3];
    const float* c      = (const float*)d_in[4];
    const float* W      = (const float*)d_in[5];
    const float* theta  = (const float*)d_in[6];
    const float* b_conv = (const float*)d_in[7];
    const float* b      = (const float*)d_in[8];
    const float* w_c    = (const float*)d_in[9];
    const float* Wcls   = (const float*)d_in[10];
    const float* bcls   = (const float*)d_in[11];

    const int N = in_sizes[0] / FDIM;
    const int E = in_sizes[2];
    const int* src = eidx;
    const int* dst = eidx + E;

    char* ws = (char*)d_ws;
    size_t off = 0;
    auto alloc = [&](size_t bytes) -> void* {
        void* p = ws + off;
        off += (bytes + 255) & ~(size_t)255;
        return p;
    };
    unsigned short* A   = (unsigned short*)alloc((size_t)N * KDIM * 2);
    unsigned short* Bt  = (unsigned short*)alloc((size_t)KDIM * KDIM * 2);
    float* cls_part     = (float*)alloc((size_t)N * 16 * 4);
    float* deg          = (float*)alloc((size_t)N * 4);
    int*   cnt          = (int*)alloc((size_t)N * 4);
    int*   cur          = (int*)alloc((size_t)N * 4);
    int*   offs         = (int*)alloc((size_t)(N + 1) * 4);
    int*   part         = (int*)alloc(64 * 4);
    int2*  csr          = (int2*)alloc((size_t)E * 8);
    (void)ws_size; (void)n_in; (void)out_size;

    float* out_cls = (float*)d_out;
    float* out_h   = out_cls + N;
    float* out_c   = out_h + (size_t)N * FDIM;

    // zero deg/cnt/cur in one async memset (consecutive allocs)
    size_t zbytes = (size_t)((char*)(cur + N) - (char*)deg);
    hipMemsetAsync(deg, 0, zbytes, stream);

    int nsb = (N + 1023) / 1024;  // <= 64
    k_degcnt<<<(E + 255) / 256, 256, 0, stream>>>(src, dst, ew, deg, cnt, E);
    k_scan1<<<nsb, 1024, 0, stream>>>(cnt, offs, part, N);
    k_scan2<<<nsb, 1024, 0, stream>>>(offs, part, N);
    k_scatter<<<(E + 255) / 256, 256, 0, stream>>>(src, dst, ew, deg, offs, cur, csr, E);
    k_packA<<<(N * 64 + 255) / 256, 256, 0, stream>>>(x, h, A, N);
    k_packBt<<<(KDIM * KDIM + 255) / 256, 256, 0, stream>>>(W, theta, Bt);
    k_prop1<<<(N * 64 + 255) / 256, 256, 0, stream>>>(A, offs, csr, N);
    k_prop2<<<(N * 64 + 255) / 256, 256, 0, stream>>>(A, h, offs, csr, N);
    int mtiles = (N + 127) / 128;
    k_gemm<<<mtiles * 8, 256, 0, stream>>>(A, Bt, c, b_conv, b, w_c, Wcls,
                                           out_h, out_c, cls_part, N, mtiles);
    k_cls<<<(N + 255) / 256, 256, 0, stream>>>(cls_part, bcls, out_cls, N);
}

// Round 6
// 190.166 us; speedup vs baseline: 1.1134x; 1.0517x over previous
//
#include <hip/hip_runtime.h>
#include <stdint.h>

#define FDIM 256
#define KDIM 1024   // 4*F : [x | h | Tx1 | Tx2]

typedef __attribute__((ext_vector_type(8))) short short8;
typedef __attribute__((ext_vector_type(4))) float floatx4;

#define GLOBAL_AS __attribute__((address_space(1)))
#define LDS_AS    __attribute__((address_space(3)))

static __device__ __forceinline__ unsigned short f2bf(float f) {
    unsigned int u = __float_as_uint(f);
    unsigned int r = (u + 0x7FFFu + ((u >> 16) & 1u)) >> 16;
    return (unsigned short)r;
}
static __device__ __forceinline__ float bf2f(unsigned short s) {
    return __uint_as_float(((unsigned int)s) << 16);
}
static __device__ __forceinline__ float sig(float x) {
    return 1.f / (1.f + __expf(-x));
}

// ---------------- fused pack-A + degree/count (saves a launch; overlaps
// atomic-bound edge stream with copy-bound pack stream) ----------------

__global__ void k_pre(const float* __restrict__ x, const float* __restrict__ h,
                      unsigned short* __restrict__ A, int n,
                      const int* __restrict__ src, const int* __restrict__ dst,
                      const float* __restrict__ ew, float* deg, int* cnt, int e) {
    int t = blockIdx.x * blockDim.x + threadIdx.x;
    if (t < e) {
        atomicAdd(&deg[src[t]], ew[t]);
        atomicAdd(&cnt[dst[t]], 1);
    }
    int node = t >> 6, q = t & 63;
    if (node >= n) return;
    floatx4 xv = *(const floatx4*)(x + (size_t)node * FDIM + q * 4);
    floatx4 hv = *(const floatx4*)(h + (size_t)node * FDIM + q * 4);
    ushort4 ox, oh;
    ox.x = f2bf(xv[0]); ox.y = f2bf(xv[1]); ox.z = f2bf(xv[2]); ox.w = f2bf(xv[3]);
    oh.x = f2bf(hv[0]); oh.y = f2bf(hv[1]); oh.z = f2bf(hv[2]); oh.w = f2bf(hv[3]);
    *(ushort4*)(A + (size_t)node * KDIM + q * 4) = ox;
    *(ushort4*)(A + (size_t)node * KDIM + FDIM + q * 4) = oh;
}

// hierarchical scan, stage 1: per-1024-block inclusive scan -> offs[i+1], block total -> part[b]
__launch_bounds__(1024)
__global__ void k_scan1(const int* __restrict__ cnt, int* __restrict__ offs,
                        int* __restrict__ part, int n) {
    __shared__ int wsum[16];
    int b = blockIdx.x;
    int i = b * 1024 + (int)threadIdx.x;
    int lane = threadIdx.x & 63;
    int wid = threadIdx.x >> 6;
    int x = (i < n) ? cnt[i] : 0;
#pragma unroll
    for (int s = 1; s < 64; s <<= 1) {
        int t = __shfl_up(x, s);
        if (lane >= s) x += t;
    }
    if (lane == 63) wsum[wid] = x;
    __syncthreads();
    if (wid == 0) {
        int y = (lane < 16) ? wsum[lane] : 0;
#pragma unroll
        for (int s = 1; s < 16; s <<= 1) {
            int t = __shfl_up(y, s);
            if (lane >= s) y += t;
        }
        if (lane < 16) wsum[lane] = y;
    }
    __syncthreads();
    int wbase = (wid > 0) ? wsum[wid - 1] : 0;
    if (i < n) offs[i + 1] = wbase + x;
    if (threadIdx.x == 1023) part[b] = wsum[15];
}

// stage 2: add exclusive prefix of part[] to each block's region (nb <= 64)
__launch_bounds__(1024)
__global__ void k_scan2(int* __restrict__ offs, const int* __restrict__ part, int n) {
    __shared__ int sprefix;
    int b = blockIdx.x;
    if (threadIdx.x < 64) {
        int p = ((int)threadIdx.x < b) ? part[threadIdx.x] : 0;
#pragma unroll
        for (int s = 32; s; s >>= 1) p += __shfl_down(p, s);
        if (threadIdx.x == 0) sprefix = p;
    }
    __syncthreads();
    int i = b * 1024 + (int)threadIdx.x;
    if (i < n) offs[i + 1] += sprefix;
    if (b == 0 && threadIdx.x == 0) offs[0] = 0;
}

// scatter with inline rsqrt normalization; CSR record packed as int2{src, w}
__global__ void k_scatter(const int* __restrict__ src, const int* __restrict__ dst,
                          const float* __restrict__ ew, const float* __restrict__ deg,
                          const int* __restrict__ offs, int* cur,
                          int2* __restrict__ csr, int e) {
    int i = blockIdx.x * blockDim.x + threadIdx.x;
    if (i < e) {
        int s = src[i], d = dst[i];
        float ds_ = deg[s], dd = deg[d];
        float rs = ds_ > 0.f ? rsqrtf(fmaxf(ds_, 1e-12f)) : 0.f;
        float rd = dd > 0.f ? rsqrtf(fmaxf(dd, 1e-12f)) : 0.f;
        float wn = -rs * ew[i] * rd;
        int pos = offs[d] + atomicAdd(&cur[d], 1);
        csr[pos] = make_int2(s, __float_as_int(wn));
    }
}

// Gate-interleaved packed B^T.
// packed col p: group=p>>6, gate=(p>>4)&3, feat=(group<<4)|(p&15)
// row r: kb=r>>8 selects {W, theta0, theta1, theta2}, rr=r&255
__global__ void k_packBt(const float* __restrict__ W, const float* __restrict__ theta,
                         unsigned short* __restrict__ Bt) {
    int t = blockIdx.x * blockDim.x + threadIdx.x; // over 1024*1024
    int p = t >> 10, r = t & 1023;
    int group = p >> 6, gate = (p >> 4) & 3;
    int feat = (group << 4) | (p & 15);
    int kb = r >> 8, rr = r & 255;
    float v;
    if (kb == 0) v = W[((size_t)(gate * FDIM + rr)) * FDIM + feat];
    else         v = theta[((size_t)((gate * 3 + (kb - 1)) * FDIM + rr)) * FDIM + feat];
    Bt[t] = f2bf(v);
}

// ---------------- sparse prop (CSR gather, wave per node, 2 half-waves x 4 unroll) ----------------

// Tx1 = prop(h): gather bf16 h from A[:,256:512], write bf16 to A[:,512:768]
__launch_bounds__(256)
__global__ void k_prop1(unsigned short* __restrict__ A, const int* __restrict__ offs,
                        const int2* __restrict__ csr, int n) {
    int wid = (blockIdx.x * blockDim.x + threadIdx.x) >> 6;
    int lane = threadIdx.x & 63;
    if (wid >= n) return;
    int half = lane >> 5, l = lane & 31;
    int beg = offs[wid], end = offs[wid + 1];
    float a[8] = {0.f, 0.f, 0.f, 0.f, 0.f, 0.f, 0.f, 0.f};
    int j = beg + half;
    for (; j + 6 < end; j += 8) {
        int2 e0 = csr[j], e1 = csr[j + 2], e2 = csr[j + 4], e3 = csr[j + 6];
        short8 v0 = *(const short8*)(A + (size_t)e0.x * KDIM + FDIM + l * 8);
        short8 v1 = *(const short8*)(A + (size_t)e1.x * KDIM + FDIM + l * 8);
        short8 v2 = *(const short8*)(A + (size_t)e2.x * KDIM + FDIM + l * 8);
        short8 v3 = *(const short8*)(A + (size_t)e3.x * KDIM + FDIM + l * 8);
        float w0 = __int_as_float(e0.y), w1 = __int_as_float(e1.y);
        float w2 = __int_as_float(e2.y), w3 = __int_as_float(e3.y);
#pragma unroll
        for (int k = 0; k < 8; ++k)
            a[k] += w0 * bf2f((unsigned short)v0[k]) + w1 * bf2f((unsigned short)v1[k])
                  + w2 * bf2f((unsigned short)v2[k]) + w3 * bf2f((unsigned short)v3[k]);
    }
    for (; j < end; j += 2) {
        int2 e0 = csr[j];
        float w0 = __int_as_float(e0.y);
        short8 v0 = *(const short8*)(A + (size_t)e0.x * KDIM + FDIM + l * 8);
#pragma unroll
        for (int k = 0; k < 8; ++k) a[k] += w0 * bf2f((unsigned short)v0[k]);
    }
#pragma unroll
    for (int k = 0; k < 8; ++k) a[k] += __shfl_xor(a[k], 32);
    if (half == 0) {
        short8 o;
#pragma unroll
        for (int k = 0; k < 8; ++k) o[k] = (short)f2bf(a[k]);
        *(short8*)(A + (size_t)wid * KDIM + 2 * FDIM + l * 8) = o;
    }
}

// Tx2 = 2*prop(Tx1) - h
__launch_bounds__(256)
__global__ void k_prop2(unsigned short* __restrict__ A, const float* __restrict__ h,
                        const int* __restrict__ offs, const int2* __restrict__ csr, int n) {
    int wid = (blockIdx.x * blockDim.x + threadIdx.x) >> 6;
    int lane = threadIdx.x & 63;
    if (wid >= n) return;
    int half = lane >> 5, l = lane & 31;
    int beg = offs[wid], end = offs[wid + 1];
    float a[8] = {0.f, 0.f, 0.f, 0.f, 0.f, 0.f, 0.f, 0.f};
    int j = beg + half;
    for (; j + 6 < end; j += 8) {
        int2 e0 = csr[j], e1 = csr[j + 2], e2 = csr[j + 4], e3 = csr[j + 6];
        short8 v0 = *(const short8*)(A + (size_t)e0.x * KDIM + 2 * FDIM + l * 8);
        short8 v1 = *(const short8*)(A + (size_t)e1.x * KDIM + 2 * FDIM + l * 8);
        short8 v2 = *(const short8*)(A + (size_t)e2.x * KDIM + 2 * FDIM + l * 8);
        short8 v3 = *(const short8*)(A + (size_t)e3.x * KDIM + 2 * FDIM + l * 8);
        float w0 = __int_as_float(e0.y), w1 = __int_as_float(e1.y);
        float w2 = __int_as_float(e2.y), w3 = __int_as_float(e3.y);
#pragma unroll
        for (int k = 0; k < 8; ++k)
            a[k] += w0 * bf2f((unsigned short)v0[k]) + w1 * bf2f((unsigned short)v1[k])
                  + w2 * bf2f((unsigned short)v2[k]) + w3 * bf2f((unsigned short)v3[k]);
    }
    for (; j < end; j += 2) {
        int2 e0 = csr[j];
        float w0 = __int_as_float(e0.y);
        short8 v0 = *(const short8*)(A + (size_t)e0.x * KDIM + 2 * FDIM + l * 8);
#pragma unroll
        for (int k = 0; k < 8; ++k) a[k] += w0 * bf2f((unsigned short)v0[k]);
    }
#pragma unroll
    for (int k = 0; k < 8; ++k) a[k] += __shfl_xor(a[k], 32);
    if (half == 0) {
        floatx4 hv0 = *(const floatx4*)(h + (size_t)wid * FDIM + l * 8);
        floatx4 hv1 = *(const floatx4*)(h + (size_t)wid * FDIM + l * 8 + 4);
        short8 o;
#pragma unroll
        for (int k = 0; k < 4; ++k) o[k] = (short)f2bf(2.f * a[k] - hv0[k]);
#pragma unroll
        for (int k = 0; k < 4; ++k) o[4 + k] = (short)f2bf(2.f * a[4 + k] - hv1[k]);
        *(short8*)(A + (size_t)wid * KDIM + 3 * FDIM + l * 8) = o;
    }
}

// ---------------- GEMM + fused LSTM epilogue (R3-proven structure) ----------------
// BK=64, XOR-swizzled LDS (linear dest + inverse-swizzled global source),
// single-buffer, 2 barriers/iter — the measured-best structure for this shape.
// Classifier partials go straight to out_cls via atomicAdd (no k_cls pass).

__launch_bounds__(256, 3)
__global__ void k_gemm(const unsigned short* __restrict__ A, const unsigned short* __restrict__ Bt,
                       const float* __restrict__ c, const float* __restrict__ b_conv,
                       const float* __restrict__ b, const float* __restrict__ w_c,
                       const float* __restrict__ Wcls, const float* __restrict__ bcls,
                       float* __restrict__ out_h, float* __restrict__ out_c,
                       float* __restrict__ out_cls, int M, int mtiles) {
    __shared__ unsigned short sA[128 * 64];
    __shared__ unsigned short sB[128 * 64];
    int tid = threadIdx.x;
    int lane = tid & 63;
    int w = tid >> 6;
    // XCD-aware swizzle: 8 consecutive nt-blocks (one A panel) land on one XCD chunk
    int nb = mtiles * 8;
    int bid = blockIdx.x;
    int wg = (bid & 7) * (nb >> 3) + (bid >> 3);
    int mt = wg >> 3;
    int nt = wg & 7;
    int brow = mt * 128, bcol = nt * 128;
    int wr = (w >> 1) * 64, wc = (w & 1) * 64;
    int l15 = lane & 15, l4 = lane >> 4;

    floatx4 acc[4][4];
#pragma unroll
    for (int m = 0; m < 4; ++m)
#pragma unroll
        for (int g = 0; g < 4; ++g)
            acc[m][g] = (floatx4){0.f, 0.f, 0.f, 0.f};

    for (int kt = 0; kt < 16; ++kt) {
        int k0 = kt * 64;
#pragma unroll
        for (int p = 0; p < 4; ++p) {
            int cch = tid + p * 256;            // 0..1023 chunks of 16B
            int row = cch >> 3, cslot = cch & 7;
            int csrc = cslot ^ (row & 7);       // inverse-swizzled source chunk
            int grow = brow + row; if (grow >= M) grow = M - 1;
            const unsigned short* g = A + (size_t)grow * KDIM + k0 + csrc * 8;
            __builtin_amdgcn_global_load_lds((const GLOBAL_AS void*)g,
                                             (LDS_AS void*)(sA + cch * 8), 16, 0, 0);
        }
#pragma unroll
        for (int p = 0; p < 4; ++p) {
            int cch = tid + p * 256;
            int row = cch >> 3, cslot = cch & 7;
            int csrc = cslot ^ (row & 7);
            const unsigned short* g = Bt + (size_t)(bcol + row) * KDIM + k0 + csrc * 8;
            __builtin_amdgcn_global_load_lds((const GLOBAL_AS void*)g,
                                             (LDS_AS void*)(sB + cch * 8), 16, 0, 0);
        }
        __syncthreads();

#pragma unroll
        for (int ks = 0; ks < 2; ++ks) {
            short8 af[4], bfr[4];
#pragma unroll
            for (int m = 0; m < 4; ++m) {
                int ra = wr + m * 16 + l15;
                af[m] = *(const short8*)(sA + ra * 64 + ((ks * 4 + l4) ^ (ra & 7)) * 8);
            }
#pragma unroll
            for (int g = 0; g < 4; ++g) {
                int rb = wc + g * 16 + l15;
                bfr[g] = *(const short8*)(sB + rb * 64 + ((ks * 4 + l4) ^ (rb & 7)) * 8);
            }
#pragma unroll
            for (int m = 0; m < 4; ++m)
#pragma unroll
                for (int g = 0; g < 4; ++g)
                    acc[m][g] = __builtin_amdgcn_mfma_f32_16x16x32_bf16(af[m], bfr[g], acc[m][g], 0, 0, 0);
        }
        __syncthreads();
    }

    // fused epilogue: this wave owns feature-group `group` for its 128-row slice
    int group = (bcol + wc) >> 6;          // 0..15
    int feat = (group << 4) | l15;         // 0..255
    float bc0 = b_conv[feat], bc1 = b_conv[FDIM + feat];
    float bc2 = b_conv[2 * FDIM + feat], bc3 = b_conv[3 * FDIM + feat];
    float bb0 = b[feat], bb1 = b[FDIM + feat];
    float bb2 = b[2 * FDIM + feat], bb3 = b[3 * FDIM + feat];
    float wci = w_c[feat], wcf = w_c[FDIM + feat], wco = w_c[2 * FDIM + feat];
    float wcl = Wcls[feat];
    float bias = (group == 0) ? bcls[0] : 0.f;

#pragma unroll
    for (int m = 0; m < 4; ++m) {
#pragma unroll
        for (int j = 0; j < 4; ++j) {
            int node = brow + wr + m * 16 + l4 * 4 + j;
            bool ok = node < M;
            int nidx = ok ? node : (M - 1);
            float cv = c[(size_t)nidx * FDIM + feat];
            float iv = sig(acc[m][0][j] + bc0 + wci * cv + bb0);
            float fv = sig(acc[m][1][j] + bc1 + wcf * cv + bb1);
            float tv = tanhf(acc[m][2][j] + bc2 + bb2);
            float cn = fv * cv + iv * tv;
            float ov = sig(acc[m][3][j] + bc3 + wco * cn + bb3);
            float hn = ov * tanhf(cn);
            if (ok) {
                out_h[(size_t)node * FDIM + feat] = hn;
                out_c[(size_t)node * FDIM + feat] = cn;
            }
            float pcls = fmaxf(hn, 0.f) * wcl;
#pragma unroll
            for (int s = 1; s < 16; s <<= 1) pcls += __shfl_xor(pcls, s);
            if (ok && l15 == 0) atomicAdd(&out_cls[node], pcls + bias);
        }
    }
}

// ---------------- launcher ----------------

extern "C" void kernel_launch(void* const* d_in, const int* in_sizes, int n_in,
                              void* d_out, int out_size, void* d_ws, size_t ws_size,
                              hipStream_t stream) {
    const float* x      = (const float*)d_in[0];
    const int*   eidx   = (const int*)d_in[1];
    const float* ew     = (const float*)d_in[2];
    const float* h      = (const float*)d_in[3];
    const float* c      = (const float*)d_in[4];
    const float* W      = (const float*)d_in[5];
    const float* theta  = (const float*)d_in[6];
    const float* b_conv = (const float*)d_in[7];
    const float* b      = (const float*)d_in[8];
    const float* w_c    = (const float*)d_in[9];
    const float* Wcls   = (const float*)d_in[10];
    const float* bcls   = (const float*)d_in[11];

    const int N = in_sizes[0] / FDIM;
    const int E = in_sizes[2];
    const int* src = eidx;
    const int* dst = eidx + E;

    char* ws = (char*)d_ws;
    size_t off = 0;
    auto alloc = [&](size_t bytes) -> void* {
        void* p = ws + off;
        off += (bytes + 255) & ~(size_t)255;
        return p;
    };
    unsigned short* A   = (unsigned short*)alloc((size_t)N * KDIM * 2);
    unsigned short* Bt  = (unsigned short*)alloc((size_t)KDIM * KDIM * 2);
    float* deg          = (float*)alloc((size_t)N * 4);
    int*   cnt          = (int*)alloc((size_t)N * 4);
    int*   cur          = (int*)alloc((size_t)N * 4);
    int*   offs         = (int*)alloc((size_t)(N + 1) * 4);
    int*   part         = (int*)alloc(64 * 4);
    int2*  csr          = (int2*)alloc((size_t)E * 8);
    (void)ws_size; (void)n_in; (void)out_size;

    float* out_cls = (float*)d_out;
    float* out_h   = out_cls + N;
    float* out_c   = out_h + (size_t)N * FDIM;

    // zero deg/cnt/cur (consecutive allocs) and the atomic classifier output
    size_t zbytes = (size_t)((char*)(cur + N) - (char*)deg);
    hipMemsetAsync(deg, 0, zbytes, stream);
    hipMemsetAsync(out_cls, 0, (size_t)N * 4, stream);

    int nsb = (N + 1023) / 1024;  // <= 64
    k_pre<<<(N * 64 + 255) / 256, 256, 0, stream>>>(x, h, A, N, src, dst, ew, deg, cnt, E);
    k_scan1<<<nsb, 1024, 0, stream>>>(cnt, offs, part, N);
    k_scan2<<<nsb, 1024, 0, stream>>>(offs, part, N);
    k_scatter<<<(E + 255) / 256, 256, 0, stream>>>(src, dst, ew, deg, offs, cur, csr, E);
    k_prop1<<<(N * 64 + 255) / 256, 256, 0, stream>>>(A, offs, csr, N);
    k_prop2<<<(N * 64 + 255) / 256, 256, 0, stream>>>(A, h, offs, csr, N);
    k_packBt<<<(KDIM * KDIM + 255) / 256, 256, 0, stream>>>(W, theta, Bt);
    int mtiles = (N + 127) / 128;
    k_gemm<<<mtiles * 8, 256, 0, stream>>>(A, Bt, c, b_conv, b, w_c, Wcls, bcls,
                                           out_h, out_c, out_cls, N, mtiles);
}